// Round 17
// baseline (114.269 us; speedup 1.0000x reference)
//
#include <hip/hip_runtime.h>

// ---------------------------------------------------------------------------
// Convnet: 8 overlapping sections, conv [32x16] x 128 ch, threshold 15, pool
// (400,16), winner-take-all -> single channel index.
//
// R17: tile-pairing + LDS-raw-X staging on the R14 base (A fp8 x B fp4).
//      Each block does both fo-tiles of one pool column (ft=2j,2j+1): one
//      W-DMA, one prologue, one pool write. Raw X (63 rows x 32 cols) loaded
//      ONCE with aligned float4 (fo0=j*16 is 64B-aligned) into a padded LDS
//      plane (stride 33 -> conflict-free); both tiles' fp8 shifted copies are
//      cvt'd from LDS, killing the 64-lane scattered gathers (64.5 KB ->
//      8 KB coalesced per pair). Tile-B staging overlaps nothing it shouldn't:
//      disjoint Ash buffer, Xraw read-only. K-loop = R14's register pipeline.
// ---------------------------------------------------------------------------

using int4v  = __attribute__((ext_vector_type(4))) int;
using int8v  = __attribute__((ext_vector_type(8))) int;
using f32x16 = __attribute__((ext_vector_type(16))) float;

#define THRESH 15.0f
#define SCALE_ONE 0x7F7F7F7F   // E8M0 127 = 2^0 per byte
#define SCALE_Q   0x7D7D7D7D   // E8M0 125 = 2^-2 per byte (undo W*4)

// positive e2m1 code for v in [0, 6.5]: values {0,.5,1,1.5,2,3,4,6}
__device__ __forceinline__ unsigned f4enc(float v) {
  float r2 = __builtin_rintf(v + v);   // step .5 band (v<=2): codes 0..4
  float r1 = __builtin_rintf(v);       // step 1 band (2<v<=4): codes 4..6
  return (v <= 2.f) ? (unsigned)r2
       : (v <= 4.f) ? (unsigned)r1 + 2u
       : (v < 5.f)  ? 6u : 7u;
}

// ---------------- prep: W fp32 -> fp4 e2m1 (x4 scale), per-section 32 KB:
//   addr = s*32768 + ch*4096 + ko*2048 + c*16   (ch = k64 chunk, ko = k32 half)
__global__ __launch_bounds__(256) void prep_kernel(const float* __restrict__ W,
                                                   unsigned char* __restrict__ Wp4,
                                                   int* __restrict__ pool) {
  int t = blockIdx.x * 256 + threadIdx.x;   // 64 blocks -> 16384 threads
  if (t < 15360) pool[t] = 0;
  int s = t >> 11, r = t & 2047, c = r >> 4, b = r & 15;   // b = k32 block
  const float* src = W + ((s * 128 + c) * 512 + b * 32);
  int4v o;
#pragma unroll
  for (int i = 0; i < 4; ++i) {
    unsigned d = 0;
#pragma unroll
    for (int e = 0; e < 8; ++e)
      d |= f4enc(fmaxf(src[i * 8 + e], 0.f) * 4.f) << (4 * e);
    o[i] = (int)d;
  }
  *(int4v*)(Wp4 + s * 32768 + (b >> 1) * 4096 + (b & 1) * 2048 + c * 16) = o;
}

// ---------------- conv + threshold + pool-OR (paired fo-tiles)
// grid: 8 s * 13 t-tiles(32) * 15 pool-cols = 1560 blocks, 256 threads
// per tile: M = 256 (32 t x 8 fo), N = 128 ch, K = 512; two tiles share s,fp.
// wave w: fo offsets {2w, 2w+1}; mfma_scale_f32_32x32x64_f8f6f4 (A fp8, B fp4)
__global__ __launch_bounds__(256, 2) void conv_pool_kernel(const float* __restrict__ X,
                                                           const unsigned char* __restrict__ Wp4,
                                                           int* __restrict__ pool) {
  __shared__ __align__(16) float Xraw[63 * 33];            // 8316 B, stride-33 pad
  __shared__ __align__(16) unsigned char Ash[2 * 8064];    // 16128 B (tile A, tile B)
  __shared__ __align__(16) unsigned char Bsh[32768];       // whole section's W, fp4
  __shared__ unsigned poolbits[32];

  const int tid = threadIdx.x;
  const int bid = blockIdx.x;
  const int s   = bid / 195;
  const int rem = bid % 195;
  const int tt  = rem / 15;
  const int j   = rem % 15;                     // pool column; tiles ft=2j,2j+1
  const int t0  = (tt == 12) ? 368 : tt * 32;   // overlap recompute; OR idempotent
  const int fo0 = j * 16;                       // 64-B aligned column base
  const int srow = s * 400 + t0;                // max 3168; +62 = 3230 in-bounds

  if (tid < 32) poolbits[tid] = 0;

  // ---- issue whole-W DMA: 2048 x 16 B, 8 per thread (drains at barrier 1)
  {
    const unsigned char* wbase = Wp4 + s * 32768;
#pragma unroll
    for (int it = 0; it < 8; ++it) {
      int off = (it * 256 + tid) * 16;
      __builtin_amdgcn_global_load_lds(
          (const __attribute__((address_space(1))) void*)(wbase + off),
          (__attribute__((address_space(3))) void*)(&Bsh[off]), 16, 0, 0);
    }
  }

  // ---- raw X load: 63 rows x 32 cols, 8 aligned float4/row (coalesced)
  for (int i = tid; i < 504; i += 256) {
    int r = i >> 3, q = i & 7;
    float4 v = *(const float4*)(X + (srow + r) * 256 + fo0 + q * 4);
    float* dst = &Xraw[r * 33 + q * 4];
    dst[0] = v.x; dst[1] = v.y; dst[2] = v.z; dst[3] = v.w;   // b32: bank-clean
  }

  f32x16 acc[2][4];
#pragma unroll
  for (int a = 0; a < 2; ++a)
#pragma unroll
    for (int b = 0; b < 4; ++b)
#pragma unroll
      for (int e = 0; e < 16; ++e) acc[a][b][e] = 0.f;

  const int w = tid >> 6, l = tid & 63;
  const int m31 = l & 31, ko = l >> 5;

  // per-lane LDS base offsets (bytes)
  const int aoff0 = (2 * w) * 1008 + m31 * 16 + ko * 32;       // + ch*64 (+16 hi)
  const int aoff1 = (2 * w + 1) * 1008 + m31 * 16 + ko * 32;
  const int boff  = ko * 2048 + m31 * 16;                      // + ch*4096 + nt*512

  __syncthreads();   // Xraw + poolbits ready (W DMA drained too)

// stage one tile's 8 fo-shifted fp8 copies from Xraw (cb = col base 0 or 8)
#define STAGE_TILE(ABASE, cb)                                                  \
  for (int i = tid; i < 504; i += 256) {                                       \
    int d = i / 63, r = i % 63;                                                \
    const float* xr = &Xraw[r * 33 + d + (cb)];                                \
    int4v pk;                                                                  \
    _Pragma("unroll")                                                          \
    for (int h = 0; h < 4; ++h) {                                              \
      int q = 0;                                                               \
      q = __builtin_amdgcn_cvt_pk_fp8_f32(xr[h * 4 + 0], xr[h * 4 + 1], q, false); \
      q = __builtin_amdgcn_cvt_pk_fp8_f32(xr[h * 4 + 2], xr[h * 4 + 3], q, true);  \
      pk[h] = q;                                                               \
    }                                                                          \
    *(int4v*)&Ash[(ABASE) + d * 1008 + r * 16] = pk;                           \
  }

// load chunk chh's fragments into named buffers (A base = tile offset)
#define LOAD_CHUNK(ABASE, chh, A0v, A1v, Bv)                                   \
  {                                                                            \
    int4v _a0lo = *(const int4v*)&Ash[(ABASE) + aoff0 + (chh) * 64];           \
    int4v _a0hi = *(const int4v*)&Ash[(ABASE) + aoff0 + (chh) * 64 + 16];      \
    int4v _a1lo = *(const int4v*)&Ash[(ABASE) + aoff1 + (chh) * 64];           \
    int4v _a1hi = *(const int4v*)&Ash[(ABASE) + aoff1 + (chh) * 64 + 16];      \
    A0v = (int8v){_a0lo[0], _a0lo[1], _a0lo[2], _a0lo[3],                      \
                  _a0hi[0], _a0hi[1], _a0hi[2], _a0hi[3]};                     \
    A1v = (int8v){_a1lo[0], _a1lo[1], _a1lo[2], _a1lo[3],                      \
                  _a1hi[0], _a1hi[1], _a1hi[2], _a1hi[3]};                     \
    const unsigned char* _bb = Bsh + (chh) * 4096 + boff;                      \
    Bv[0] = *(const int4v*)(_bb);                                              \
    Bv[1] = *(const int4v*)(_bb + 512);                                        \
    Bv[2] = *(const int4v*)(_bb + 1024);                                       \
    Bv[3] = *(const int4v*)(_bb + 1536);                                       \
  }

// 8 MFMAs on a buffer set (A fp8 cbsz=0, B fp4 blgp=4, B scale 2^-2)
#define MFMA_CHUNK(A0v, A1v, Bv)                                               \
  {                                                                            \
    _Pragma("unroll")                                                          \
    for (int nt = 0; nt < 4; ++nt) {                                           \
      int8v Bf = {Bv[nt][0], Bv[nt][1], Bv[nt][2], Bv[nt][3], 0, 0, 0, 0};     \
      acc[0][nt] = __builtin_amdgcn_mfma_scale_f32_32x32x64_f8f6f4(            \
          A0v, Bf, acc[0][nt], 0, 4, 0, SCALE_ONE, 0, SCALE_Q);                \
      acc[1][nt] = __builtin_amdgcn_mfma_scale_f32_32x32x64_f8f6f4(            \
          A1v, Bf, acc[1][nt], 0, 4, 0, SCALE_ONE, 0, SCALE_Q);                \
    }                                                                          \
  }

// barrier-free, register-pipelined K loop over 8 chunks (R14 structure)
#define KLOOP(ABASE)                                                           \
  {                                                                            \
    int8v A0a, A1a, A0b, A1b;                                                  \
    int4v Ba[4], Bb[4];                                                        \
    LOAD_CHUNK(ABASE, 0, A0a, A1a, Ba);                                        \
    _Pragma("unroll 1")                                                        \
    for (int ch = 0; ch < 8; ch += 2) {                                        \
      LOAD_CHUNK(ABASE, ch + 1, A0b, A1b, Bb);                                 \
      MFMA_CHUNK(A0a, A1a, Ba);                                                \
      int chn = (ch + 2 < 8) ? ch + 2 : 7;                                     \
      LOAD_CHUNK(ABASE, chn, A0a, A1a, Ba);                                    \
      MFMA_CHUNK(A0b, A1b, Bb);                                                \
    }                                                                          \
  }

// threshold over the wave's accumulators -> 4-bit nt mask
#define EXTRACT_SP(spv)                                                        \
  {                                                                            \
    spv = 0;                                                                   \
    _Pragma("unroll")                                                          \
    for (int nt = 0; nt < 4; ++nt) {                                           \
      float m0 = -1e30f, m1 = -1e30f;                                          \
      _Pragma("unroll")                                                        \
      for (int e = 0; e < 16; ++e) {                                           \
        m0 = fmaxf(m0, acc[0][nt][e]);                                         \
        m1 = fmaxf(m1, acc[1][nt][e]);                                         \
      }                                                                        \
      if (fmaxf(m0, m1) >= THRESH) spv |= (1u << nt);                          \
    }                                                                          \
  }

  // ---- tile A (fo = fo0..fo0+7)
  STAGE_TILE(0, 0)
  __syncthreads();   // AshA ready
  KLOOP(0)
  unsigned spA;
  EXTRACT_SP(spA)

  // ---- tile B (fo = fo0+8..fo0+15): stage from Xraw (disjoint Ash buffer)
#pragma unroll
  for (int a = 0; a < 2; ++a)
#pragma unroll
    for (int b = 0; b < 4; ++b)
#pragma unroll
      for (int e = 0; e < 16; ++e) acc[a][b][e] = 0.f;
  STAGE_TILE(8064, 8)
  __syncthreads();   // AshB ready (all waves done reading AshA)
  KLOOP(8064)
  unsigned spB;
  EXTRACT_SP(spB)

  // ---- combined OR epilogue. Lane covers channels c = nt*32 + m31.
  unsigned sp = spA | spB;
  sp |= __shfl_xor(sp, 32, 64);   // merge the two row-halves
  if (l < 32 && sp) atomicOr(&poolbits[m31], sp);
  __syncthreads();

  if (tid < 128) {
    unsigned bits = poolbits[tid & 31];
    if ((bits >> (tid >> 5)) & 1)
      pool[(s * 128 + tid) * 15 + j] = 1;   // benign same-value race across blocks
  }
}

// ---------------- winner (reference get_k_winners semantics), pool in LDS
__global__ __launch_bounds__(256) void winner_kernel(const int* __restrict__ pool,
                                                     float* __restrict__ out) {
  __shared__ int lp[15360];
  __shared__ int sh_v;
  __shared__ int sh_best;
  int tid = threadIdx.x;
  if (tid == 0) { sh_v = 0; sh_best = 0; }
  for (int i = tid; i < 15360; i += 256) lp[i] = pool[i];
  __syncthreads();

  int localv = 0;
  for (int p = tid; p < 1920; p += 256) {
    int c = p / 15, f = p % 15;
    int cnt = 0;
    for (int s = 0; s < 8; ++s) cnt += lp[(s * 128 + c) * 15 + f];
    if (cnt > 0) {
      int early = 8 - cnt; if (early > 7) early = 7;
      localv |= lp[(early * 128 + c) * 15 + f];
    }
  }
  if (localv) atomicOr(&sh_v, 1);
  __syncthreads();

  const int v = sh_v * 8;   // trunc.max() * T
  int localbest = 0;
  for (int p = tid; p < 1920; p += 256) {
    int c = p / 15, f = p % 15;
    int cnt = 0;
    for (int s = 0; s < 8; ++s) cnt += lp[(s * 128 + c) * 15 + f];
    int early = 8 - cnt; if (early > 7) early = 7;
    int val = lp[(early * 128 + c) * 15 + f];
    int total = cnt * (val + v);
    int pack = (total << 12) | (4095 - p);   // max total, then smallest flat idx
    if (pack > localbest) localbest = pack;
  }
  atomicMax(&sh_best, localbest);
  __syncthreads();

  if (tid == 0) {
    int total = sh_best >> 12;
    int p = 4095 - (sh_best & 4095);
    int feat = p / 15;
    out[0] = (total != 0) ? (float)feat : -1.0f;
  }
}

// ---------------------------------------------------------------------------
extern "C" void kernel_launch(void* const* d_in, const int* in_sizes, int n_in,
                              void* d_out, int out_size, void* d_ws, size_t ws_size,
                              hipStream_t stream) {
  (void)in_sizes; (void)n_in; (void)out_size; (void)ws_size;
  const float* X = (const float*)d_in[0];
  const float* W = (const float*)d_in[1];
  unsigned char* Wp4 = (unsigned char*)d_ws;               // 262,144 B
  int* pool = (int*)((char*)d_ws + (1 << 18));             // 61,440 B

  prep_kernel<<<64, 256, 0, stream>>>(W, Wp4, pool);
  conv_pool_kernel<<<1560, 256, 0, stream>>>(X, Wp4, pool);
  winner_kernel<<<1, 256, 0, stream>>>(pool, (float*)d_out);
}